// Round 4
// baseline (489.187 us; speedup 1.0000x reference)
//
#include <hip/hip_runtime.h>
#include <hip/hip_bf16.h>

#define DEV __device__ __forceinline__

typedef unsigned short u16;
typedef __attribute__((ext_vector_type(4))) float f32x4;
typedef __attribute__((ext_vector_type(8))) short s16x8;

// problem constants
static constexpr int Bc = 2, Hc = 16, Sc = 4096, Dc = 1024, HDc = 64;

DEV u16 f2bf(float f) {
  unsigned x = __float_as_uint(f);
  x += 0x7FFFu + ((x >> 16) & 1u);   // RNE
  return (u16)(x >> 16);
}
DEV float bf2f(u16 u) { return __uint_as_float(((unsigned)u) << 16); }

DEV unsigned cvtpk_bf16(float lo, float hi) {   // word = bf16(lo) | bf16(hi)<<16
  unsigned r;
  asm("v_cvt_pk_bf16_f32 %0, %1, %2" : "=v"(r) : "v"(lo), "v"(hi));
  return r;
}

DEV void gload_lds16(const void* g, void* l) {
  __builtin_amdgcn_global_load_lds((const __attribute__((address_space(1))) void*)g,
                                   (__attribute__((address_space(3))) void*)l, 16, 0, 0);
}

DEV f32x4 mfma16(s16x8 a, s16x8 b, f32x4 c) {
  return __builtin_amdgcn_mfma_f32_16x16x32_bf16(a, b, c, 0, 0, 0);
}

DEV f32x4 fzero4() { f32x4 v; v[0] = v[1] = v[2] = v[3] = 0.f; return v; }

// ---------------- elementwise f32 -> bf16 ----------------
__global__ void cvt_f32_bf16(const float* __restrict__ in, u16* __restrict__ out, size_t n) {
  size_t i = ((size_t)blockIdx.x * blockDim.x + threadIdx.x) * 4;
  size_t stride = (size_t)gridDim.x * blockDim.x * 4;
  for (; i < n; i += stride) {
    float4 v = *(const float4*)(in + i);
    u16 a = f2bf(v.x), b = f2bf(v.y), c = f2bf(v.z), d = f2bf(v.w);
    *(ushort4*)(out + i) = make_ushort4(a, b, c, d);
  }
}

// ---------------- transpose + convert: out[c][r] = bf16(in[r][c]) ----------------
__global__ void transpose_cvt(const float* __restrict__ in, u16* __restrict__ out, int R, int C) {
  __shared__ u16 t[64][72];
  int nct = C >> 6;
  int tr = blockIdx.x / nct, tc = blockIdx.x % nct;
  int r0 = tr << 6, c0 = tc << 6;
  int lr = threadIdx.x >> 2;
  int lc0 = (threadIdx.x & 3) << 4;
  const float* src = in + (size_t)(r0 + lr) * C + c0 + lc0;
#pragma unroll
  for (int j = 0; j < 16; j += 4) {
    float4 v = *(const float4*)(src + j);
    t[lr][lc0 + j + 0] = f2bf(v.x);
    t[lr][lc0 + j + 1] = f2bf(v.y);
    t[lr][lc0 + j + 2] = f2bf(v.z);
    t[lr][lc0 + j + 3] = f2bf(v.w);
  }
  __syncthreads();
  u16* dst = out + (size_t)(c0 + lr) * R + r0 + lc0;
#pragma unroll
  for (int j = 0; j < 16; j += 4) {
    u16 a = t[lc0 + j + 0][lr], b = t[lc0 + j + 1][lr], c = t[lc0 + j + 2][lr], d = t[lc0 + j + 3][lr];
    *(ushort4*)(dst + j) = make_ushort4(a, b, c, d);
  }
}

// ---------------- GEMM: C[m][n] = A[m][:] . BT[n][:] + bias[n] ----------------
template <int MODE>
__global__ __launch_bounds__(256, 2) void gemm128(
    const u16* __restrict__ A, const u16* __restrict__ BT, const float* __restrict__ bias,
    void* __restrict__ out0, u16* __restrict__ out1, u16* __restrict__ out2,
    int N, int K, int grid_n) {
  __shared__ u16 Al[128 * 64];
  __shared__ u16 Bl[128 * 64];
  int bid = blockIdx.x;
  int bn = bid % grid_n, bm = bid / grid_n;
  int m0 = bm * 128, n0 = bn * 128;
  int tid = threadIdx.x, lane = tid & 63, wid = tid >> 6;
  int wm = wid >> 1, wn = wid & 1;
  int fr = lane & 15, fg = lane >> 4;

  f32x4 acc[4][4];
#pragma unroll
  for (int mi = 0; mi < 4; ++mi)
#pragma unroll
    for (int ni = 0; ni < 4; ++ni) acc[mi][ni] = fzero4();

  for (int kt = 0; kt < K; kt += 64) {
    const u16* Ag = A + (size_t)m0 * K + kt;
    const u16* Bg = BT + (size_t)n0 * K + kt;
#pragma unroll
    for (int it = 0; it < 4; ++it) {
      int L = it * 4096 + wid * 1024 + lane * 16;  // byte offset in 16KB tile
      int row = L >> 7;
      int sch = ((L >> 4) & 7) ^ (row & 7);
      gload_lds16(Ag + (size_t)row * K + sch * 8, (char*)Al + it * 4096 + wid * 1024);
      gload_lds16(Bg + (size_t)row * K + sch * 8, (char*)Bl + it * 4096 + wid * 1024);
    }
    __syncthreads();
#pragma unroll
    for (int c = 0; c < 2; ++c) {
      s16x8 af[4], bfr[4];
#pragma unroll
      for (int mi = 0; mi < 4; ++mi) {
        int row = wm * 64 + mi * 16 + fr;
        int ch = (c * 4 + fg) ^ (row & 7);
        af[mi] = *(const s16x8*)((const char*)Al + row * 128 + ch * 16);
      }
#pragma unroll
      for (int ni = 0; ni < 4; ++ni) {
        int row = wn * 64 + ni * 16 + fr;
        int ch = (c * 4 + fg) ^ (row & 7);
        bfr[ni] = *(const s16x8*)((const char*)Bl + row * 128 + ch * 16);
      }
#pragma unroll
      for (int mi = 0; mi < 4; ++mi)
#pragma unroll
        for (int ni = 0; ni < 4; ++ni) acc[mi][ni] = mfma16(af[mi], bfr[ni], acc[mi][ni]);
    }
    __syncthreads();
  }

  if constexpr (MODE == 0) {
    u16* qb = (u16*)out0;
    u16* kb = out1;
    u16* vT = out2;
#pragma unroll
    for (int ni = 0; ni < 4; ++ni) {
      int n = n0 + wn * 64 + ni * 16 + fr;
      float bv = bias[n];
      int h = n / 192;
      int c = n % 192;
      int part = c >> 6;
      int e = c & 63;
#pragma unroll
      for (int mi = 0; mi < 4; ++mi) {
        int m = m0 + wm * 64 + mi * 16 + fg * 4;
        int b = m >> 12;
        int s = m & 4095;
        size_t bh = (size_t)b * Hc + h;
        if (part == 2) {
          u16 a0 = f2bf(acc[mi][ni][0] + bv), a1 = f2bf(acc[mi][ni][1] + bv);
          u16 a2 = f2bf(acc[mi][ni][2] + bv), a3 = f2bf(acc[mi][ni][3] + bv);
          *(ushort4*)(vT + ((bh * HDc + e) * (size_t)Sc + s)) = make_ushort4(a0, a1, a2, a3);
        } else {
          u16* dst = (part == 0 ? qb : kb) + ((bh * Sc + s) * (size_t)HDc + e);
#pragma unroll
          for (int r = 0; r < 4; ++r) dst[(size_t)r * HDc] = f2bf(acc[mi][ni][r] + bv);
        }
      }
    }
  } else {
    float* O = (float*)out0;
#pragma unroll
    for (int ni = 0; ni < 4; ++ni) {
      int n = n0 + wn * 64 + ni * 16 + fr;
      float bv = bias[n];
#pragma unroll
      for (int mi = 0; mi < 4; ++mi) {
        int m = m0 + wm * 64 + mi * 16 + fg * 4;
#pragma unroll
        for (int r = 0; r < 4; ++r) O[(size_t)(m + r) * N + n] = acc[mi][ni][r] + bv;
      }
    }
  }
}

// ---------------- flash attention ----------------
// Swapped QK^T (q lane-local), single-buffered K/V in LDS (25KB total -> 6 blocks/CU),
// T14 async-STAGE: global->reg loads for tile t+1 issued before compute of t,
// ds_write after barrier. Barriers never wait on global loads.
// block: 256 threads = 4 waves; lane (fr,fg) owns q-row q0+wid*16+fr.
__global__ __launch_bounds__(256, 6) void attn_kernel(
    const u16* __restrict__ qb, const u16* __restrict__ kb, const u16* __restrict__ vT,
    const float* __restrict__ maskp, u16* __restrict__ vals) {
  __shared__ u16 Kl[64 * 64];        // 8KB, XOR-8 swizzled rows
  __shared__ u16 Vl[64 * 64];        // 8KB
  __shared__ char Pl[4 * 16 * 144];  // per-wave [16 q][64 k] bf16, 144B rows

  // XCD-bijective swizzle: physical p*8+x -> logical x*256+p
  int bid = ((blockIdx.x & 7) << 8) | (blockIdx.x >> 3);
  int h = bid & 15, b = (bid >> 4) & 1, qt = bid >> 5;
  int tid = threadIdx.x;
  int lane = tid & 63, wid = tid >> 6;
  int fr = lane & 15, fg = lane >> 4;
  size_t bh = (size_t)b * Hc + h;
  int q0 = qt * 64;
  int q = q0 + wid * 16 + fr;      // this lane's q-row

  const u16* Qrow = qb + ((bh * Sc) + q) * (size_t)HDc;
  s16x8 qa0 = *(const s16x8*)(Qrow + fg * 8);
  s16x8 qa1 = *(const s16x8*)(Qrow + 32 + fg * 8);

  f32x4 o[4];                       // o[ef][r] = O[e=ef*16+fg*4+r][q]
#pragma unroll
  for (int ef = 0; ef < 4; ++ef) o[ef] = fzero4();
  float mrun = -1e30f, lrun = 0.f;

  const u16* Kg = kb + bh * (size_t)Sc * HDc;
  const u16* Vg = vT + bh * (size_t)HDc * Sc;
  char* pw = (char*)Pl + wid * 2304 + fr * 144;
  const float SCALE = 0.125f;
  const float LOG2E = 1.44269504088896340736f;

  // staging: each thread owns bytes {j*4096 + tid*16 : j=0,1} of the 8KB tile.
  // row = j*32 + (tid>>3), chunk e = tid&7; LDS dest chunk swizzled by row&7.
  int e8 = tid & 7;
  int r5 = tid >> 3;               // 0..31
  int rr = r5 & 7;
  int swc = (e8 ^ rr) << 4;
  int ldsw0 = (0 * 32 + r5) * 128 + swc;
  int ldsw1 = (1 * 32 + r5) * 128 + swc;
  const u16* KgL0 = Kg + (size_t)(0 * 32 + r5) * HDc + e8 * 8;
  const u16* KgL1 = Kg + (size_t)(1 * 32 + r5) * HDc + e8 * 8;
  const u16* VgL0 = Vg + (size_t)(0 * 32 + r5) * Sc + e8 * 8;
  const u16* VgL1 = Vg + (size_t)(1 * 32 + r5) * Sc + e8 * 8;

  // fragment-read byte offsets (XOR-8 swizzled chunks)
  int kroff0 = fr * 128 + ((fg ^ (fr & 7)) << 4);
  int kroff1 = fr * 128 + (((4 + fg) ^ (fr & 7)) << 4);

  const float* mk = maskp + ((size_t)b * Sc + q) * Sc;

  // prologue: stage tile 0 (reg -> LDS)
  {
    uint4 k0 = *(const uint4*)(KgL0);
    uint4 k1 = *(const uint4*)(KgL1);
    uint4 v0 = *(const uint4*)(VgL0);
    uint4 v1 = *(const uint4*)(VgL1);
    *(uint4*)((char*)Kl + ldsw0) = k0;
    *(uint4*)((char*)Kl + ldsw1) = k1;
    *(uint4*)((char*)Vl + ldsw0) = v0;
    *(uint4*)((char*)Vl + ldsw1) = v1;
  }
  __syncthreads();

  for (int kt = 0; kt < Sc / 64; ++kt) {
    // issue next-tile loads into regs (latency hides under compute below)
    int ktn = (kt < Sc / 64 - 1) ? kt + 1 : kt;
    uint4 kn0 = *(const uint4*)(KgL0 + (size_t)ktn * 4096);
    uint4 kn1 = *(const uint4*)(KgL1 + (size_t)ktn * 4096);
    uint4 vn0 = *(const uint4*)(VgL0 + (size_t)ktn * 64);
    uint4 vn1 = *(const uint4*)(VgL1 + (size_t)ktn * 64);

    // mask loads (f32)
    const float* mrow = mk + kt * 64 + fg * 4;
    float4 mf0 = *(const float4*)(mrow);
    float4 mf1 = *(const float4*)(mrow + 16);
    float4 mf2 = *(const float4*)(mrow + 32);
    float4 mf3 = *(const float4*)(mrow + 48);

    // swapped QK^T: sa[f][r] = S[key = f*16+fg*4+r][q]
    f32x4 sa[4];
#pragma unroll
    for (int f = 0; f < 4; ++f) sa[f] = fzero4();
    __builtin_amdgcn_s_setprio(1);
#pragma unroll
    for (int f = 0; f < 4; ++f) {
      s16x8 kf = *(const s16x8*)((const char*)Kl + f * 2048 + kroff0);
      sa[f] = mfma16(kf, qa0, sa[f]);
    }
#pragma unroll
    for (int f = 0; f < 4; ++f) {
      s16x8 kf = *(const s16x8*)((const char*)Kl + f * 2048 + kroff1);
      sa[f] = mfma16(kf, qa1, sa[f]);
    }
    __builtin_amdgcn_s_setprio(0);

    // scale + mask
    float t[4][4];
#pragma unroll
    for (int r = 0; r < 4; ++r) {
      t[0][r] = fmaf(sa[0][r], SCALE, (&mf0.x)[r]);
      t[1][r] = fmaf(sa[1][r], SCALE, (&mf1.x)[r]);
      t[2][r] = fmaf(sa[2][r], SCALE, (&mf2.x)[r]);
      t[3][r] = fmaf(sa[3][r], SCALE, (&mf3.x)[r]);
    }

    // tile max + cross-lane over fg groups
    float x0 = fmaxf(fmaxf(t[0][0], t[0][1]), t[0][2]);
    float x1 = fmaxf(fmaxf(t[0][3], t[1][0]), t[1][1]);
    float x2 = fmaxf(fmaxf(t[1][2], t[1][3]), t[2][0]);
    float x3 = fmaxf(fmaxf(t[2][1], t[2][2]), t[2][3]);
    float x4 = fmaxf(fmaxf(t[3][0], t[3][1]), t[3][2]);
    float mt = fmaxf(fmaxf(fmaxf(x0, x1), x2), fmaxf(fmaxf(x3, x4), t[3][3]));
    mt = fmaxf(mt, __shfl_xor(mt, 16, 64));
    mt = fmaxf(mt, __shfl_xor(mt, 32, 64));

    // defer-max: rescale only when the wave's max grew past threshold
    if (!__all(mt <= mrun + 8.0f)) {
      float mnew = fmaxf(mrun, mt);
      float al = __builtin_amdgcn_exp2f((mrun - mnew) * LOG2E);
      mrun = mnew;
      lrun *= al;
#pragma unroll
      for (int ef = 0; ef < 4; ++ef) o[ef] *= al;
    }

    float nm = -mrun * LOG2E;
    float p[4][4];
    float ss0 = 0.f, ss1 = 0.f;
#pragma unroll
    for (int f = 0; f < 4; ++f) {
      float p0 = __builtin_amdgcn_exp2f(fmaf(t[f][0], LOG2E, nm));
      float p1 = __builtin_amdgcn_exp2f(fmaf(t[f][1], LOG2E, nm));
      float p2 = __builtin_amdgcn_exp2f(fmaf(t[f][2], LOG2E, nm));
      float p3 = __builtin_amdgcn_exp2f(fmaf(t[f][3], LOG2E, nm));
      p[f][0] = p0; p[f][1] = p1; p[f][2] = p2; p[f][3] = p3;
      ss0 += (p0 + p1);
      ss1 += (p2 + p3);
    }
    float ssum = ss0 + ss1;
    ssum += __shfl_xor(ssum, 16, 64);
    ssum += __shfl_xor(ssum, 32, 64);
    lrun += ssum;

    // P -> per-wave LDS via packed cvt
#pragma unroll
    for (int f = 0; f < 4; ++f) {
      uint2 pk;
      pk.x = cvtpk_bf16(p[f][0], p[f][1]);
      pk.y = cvtpk_bf16(p[f][2], p[f][3]);
      *(uint2*)(pw + f * 32 + fg * 8) = pk;
    }

    // PV: O^T[e][q] += V^T[e][k] * P[q][k]
    s16x8 pa0 = *(const s16x8*)(pw + fg * 16);
    s16x8 pa1 = *(const s16x8*)(pw + 64 + fg * 16);
    __builtin_amdgcn_s_setprio(1);
#pragma unroll
    for (int ef = 0; ef < 4; ++ef) {
      s16x8 vf = *(const s16x8*)((const char*)Vl + ef * 2048 + kroff0);
      o[ef] = mfma16(vf, pa0, o[ef]);
    }
#pragma unroll
    for (int ef = 0; ef < 4; ++ef) {
      s16x8 vf = *(const s16x8*)((const char*)Vl + ef * 2048 + kroff1);
      o[ef] = mfma16(vf, pa1, o[ef]);
    }
    __builtin_amdgcn_s_setprio(0);

    __syncthreads();                 // all waves done reading tile kt
    *(uint4*)((char*)Kl + ldsw0) = kn0;   // vmcnt wait auto-inserted on reg use
    *(uint4*)((char*)Kl + ldsw1) = kn1;
    *(uint4*)((char*)Vl + ldsw0) = vn0;
    *(uint4*)((char*)Vl + ldsw1) = vn1;
    __syncthreads();                 // tile kt+1 visible
  }

  // epilogue: normalize + store to vals in [B,H,S,HD]-flat order
  float inv = 1.f / lrun;
  u16* vbase = vals + (size_t)b * Sc * Dc + (size_t)h * Sc * HDc + (size_t)q * HDc;
#pragma unroll
  for (int ef = 0; ef < 4; ++ef) {
    ushort4 ov = make_ushort4(f2bf(o[ef][0] * inv), f2bf(o[ef][1] * inv),
                              f2bf(o[ef][2] * inv), f2bf(o[ef][3] * inv));
    *(ushort4*)(vbase + ef * 16 + fg * 4) = ov;
  }
}

extern "C" void kernel_launch(void* const* d_in, const int* in_sizes, int n_in,
                              void* d_out, int out_size, void* d_ws, size_t ws_size,
                              hipStream_t stream) {
  (void)in_sizes; (void)n_in; (void)out_size; (void)ws_size;
  const float* x    = (const float*)d_in[0];
  const float* mask = (const float*)d_in[1];
  const float* Wqkv = (const float*)d_in[2];
  const float* bqkv = (const float*)d_in[3];
  const float* Wo   = (const float*)d_in[4];
  const float* bo   = (const float*)d_in[5];
  float* out = (float*)d_out;
  char* ws = (char*)d_ws;

  u16* xb    = (u16*)(ws + 0);          // 16.8 MB   x as bf16 [8192][1024]
  u16* wqkvT = (u16*)(ws + 16777216);   // 6.3 MB    Wqkv^T bf16 [3072][1024]
  u16* woT   = (u16*)(ws + 23068672);   // 2.1 MB    Wo^T bf16 [1024][1024]
  u16* qb    = (u16*)(ws + 25165824);   // 16.8 MB   Q bf16 [B,H,S,64]
  u16* kb    = (u16*)(ws + 41943040);   // 16.8 MB   K bf16 [B,H,S,64]
  u16* vT    = (u16*)(ws + 58720256);   // 16.8 MB   V^T bf16 [B,H,64,S]
  u16* vals  = (u16*)(ws + 75497472);   // 16.8 MB   attn out bf16 (reshaped layout)

  cvt_f32_bf16<<<dim3(2048), dim3(256), 0, stream>>>(x, xb, (size_t)8388608);
  transpose_cvt<<<dim3(768), dim3(256), 0, stream>>>(Wqkv, wqkvT, 1024, 3072);
  transpose_cvt<<<dim3(256), dim3(256), 0, stream>>>(Wo, woT, 1024, 1024);

  gemm128<0><<<dim3(1536), dim3(256), 0, stream>>>(xb, wqkvT, bqkv, (void*)qb, kb, vT,
                                                   3072, 1024, 24);
  attn_kernel<<<dim3(2048), dim3(256), 0, stream>>>(qb, kb, vT, mask, vals);
  gemm128<1><<<dim3(512), dim3(256), 0, stream>>>(vals, woT, bo, (void*)out, nullptr, nullptr,
                                                  1024, 1024, 8);
}